// Round 9
// baseline (79.683 us; speedup 1.0000x reference)
//
#include <hip/hip_runtime.h>
#include <hip/hip_bf16.h>
#include <stdint.h>

#define TEMPERATURE 0.07f
#define SC 20.6099312f   // log2(e)/T  (SC*ln2 == 1/T exactly in math; cancellation used in k_rowfin)

constexpr int NQ = 256;
constexpr int KQ = 8192;
constexpr int D  = 128;
constexpr int N  = NQ + 2 * KQ;   // 16640
constexpr int CS = 26;            // column splits (130 tiles / 26 = exactly 5 per block)
constexpr int BN = 128;           // columns per tile (fp8 tile = 16KB)
constexpr int RBM = N / 128;      // 130 row blocks for k_main
constexpr int RBF = N / 256;      // 65 blocks for k_rowfin

typedef float f32x16 __attribute__((ext_vector_type(16)));
typedef int   i32x4  __attribute__((ext_vector_type(4)));
typedef int   i32x8  __attribute__((ext_vector_type(8)));

// ---- workspace layout (bytes) ----
constexpr size_t OFF_F32  = 0;                                    // float feat [NQ][D] (q rows only)
constexpr size_t OFF_8    = OFF_F32  + (size_t)NQ * D * 4;        // fp8 feat (A side) [N][128]
constexpr size_t OFF_8S   = OFF_8    + (size_t)N * D;             // fp8 feat * SC (B side) [N][128]
constexpr size_t OFF_PART = OFF_8S   + (size_t)N * D;             // partials [CS][N]
constexpr size_t OFF_LP   = OFF_PART + (size_t)CS * N * 4;        // label partials [260][2][128]
constexpr size_t OFF_BSUM = OFF_LP   + (size_t)260 * 2 * 128 * 4; // blocksum [65]

#define MFMA8(a, b, c) __builtin_amdgcn_mfma_scale_f32_32x32x64_f8f6f4( \
    (a), (b), (c), 0, 0, 0, 0x7f7f7f7f, 0, 0x7f7f7f7f)

// ---------------------------------------------------------------------------
// K1: normalize features; emit f32 (q rows only) + two natural-row-major fp8
// copies (unscaled A side, SC-prescaled B side); per-label per-dim partials.
// ---------------------------------------------------------------------------
__global__ __launch_bounds__(256) void k_prep(const float* __restrict__ q,
                                              const float* __restrict__ ba,
                                              const float* __restrict__ nb,
                                              const long long* __restrict__ tgt,
                                              float* __restrict__ ff,
                                              unsigned char* __restrict__ fb8,
                                              unsigned char* __restrict__ fb8s,
                                              float* __restrict__ lp) {
    __shared__ float red[4][2][128];
    int wid = threadIdx.x >> 6, lane = threadIdx.x & 63;
    int rbase = blockIdx.x * 64 + wid * 16;
    float s0x = 0.f, s0y = 0.f, s1x = 0.f, s1y = 0.f;
    for (int i = 0; i < 16; ++i) {
        int r = rbase + i;
        const float* src = (r < NQ) ? (q + (size_t)r * D)
                         : (r < NQ + KQ) ? (ba + (size_t)(r - NQ) * D)
                         : (nb + (size_t)(r - NQ - KQ) * D);
        float2 v = *(const float2*)(src + lane * 2);
        float a = v.x, b = v.y;
        int lab;
        if (r < NQ) {
            float ss = a * a + b * b;
            #pragma unroll
            for (int m = 1; m < 64; m <<= 1) ss += __shfl_xor(ss, m);
            float scale = 1.0f / fmaxf(sqrtf(ss), 1e-12f);
            a *= scale; b *= scale;
            lab = (int)tgt[r];
            *(float2*)(ff + (size_t)r * D + lane * 2) = make_float2(a, b);
        } else {
            lab = (r < NQ + KQ) ? 1 : 0;
        }
        int w8  = __builtin_amdgcn_cvt_pk_fp8_f32(a, b, 0, false);
        int w8s = __builtin_amdgcn_cvt_pk_fp8_f32(a * SC, b * SC, 0, false);
        *(unsigned short*)(fb8  + (size_t)r * D + lane * 2) = (unsigned short)w8;
        *(unsigned short*)(fb8s + (size_t)r * D + lane * 2) = (unsigned short)w8s;
        if (lab) { s1x += a; s1y += b; } else { s0x += a; s0y += b; }
    }
    red[wid][0][lane * 2]     = s0x;
    red[wid][0][lane * 2 + 1] = s0y;
    red[wid][1][lane * 2]     = s1x;
    red[wid][1][lane * 2 + 1] = s1y;
    __syncthreads();
    int lab2 = threadIdx.x >> 7, d = threadIdx.x & 127;
    float s = red[0][lab2][d] + red[1][lab2][d] + red[2][lab2][d] + red[3][lab2][d];
    lp[((size_t)blockIdx.x * 2 + lab2) * 128 + d] = s;
}

// A-operand fetch from swizzled LDS tile (R7-verified 0-conflict layout).
__device__ __forceinline__ i32x8 lda(const unsigned char* buf, int wc, int l31,
                                     int lhi, int s, int cc) {
    int crow = wc * 64 + cc * 32 + l31;
    int line = crow >> 1;
    int pb = ((crow & 1) << 3) + s * 4 + lhi * 2;
    const unsigned char* lb = buf + line * 256;
    i32x4 lo = *(const i32x4*)(lb + ((pb    ) ^ (line & 15)) * 16);
    i32x4 hi = *(const i32x4*)(lb + ((pb + 1) ^ (line & 15)) * 16);
    i32x8 a = {lo[0], lo[1], lo[2], lo[3], hi[0], hi[1], hi[2], hi[3]};
    return a;
}

// One super-phase: MFMA this tile into acc[][] while (optionally) running the
// exp-epilogue of the PREVIOUS tile (pacc) interleaved 8-at-a-time between
// consecutive MFMAs, so trans-pipe work hides under matrix-pipe occupancy.
// FIN(c): group g=c>>1 -> pacc[cc=(c>>2)&1][rs=(c>>1)&1], half h=c&1.
#define FIN(c) if (dofin) { const f32x16& A = pacc[((c) >> 2) & 1][((c) >> 1) & 1]; \
    float s_ = 0.f; \
    _Pragma("unroll") \
    for (int e = 0; e < 8; ++e) s_ += __builtin_amdgcn_exp2f(A[(((c) & 1) << 3) + e]); \
    ps[((c) >> 1) & 1] += s_; }

__device__ __forceinline__ void phase(const unsigned char* buf,
                                      f32x16 (&acc)[2][2], const f32x16 (&pacc)[2][2],
                                      const i32x8 (&rf)[2][2], const f32x16& z16,
                                      int wc, int l31, int lhi, bool dofin,
                                      float (&rsum)[2]) {
    i32x8 a00 = lda(buf, wc, l31, lhi, 0, 0);
    i32x8 a10 = lda(buf, wc, l31, lhi, 1, 0);
    i32x8 a01 = lda(buf, wc, l31, lhi, 0, 1);
    i32x8 a11 = lda(buf, wc, l31, lhi, 1, 1);
    float ps[2] = {0.f, 0.f};
    acc[0][0] = MFMA8(a00, rf[0][0], z16);       FIN(0)
    acc[0][0] = MFMA8(a10, rf[0][1], acc[0][0]); FIN(1)
    acc[0][1] = MFMA8(a00, rf[1][0], z16);       FIN(2)
    acc[0][1] = MFMA8(a10, rf[1][1], acc[0][1]); FIN(3)
    acc[1][0] = MFMA8(a01, rf[0][0], z16);       FIN(4)
    acc[1][0] = MFMA8(a11, rf[0][1], acc[1][0]); FIN(5)
    acc[1][1] = MFMA8(a01, rf[1][0], z16);       FIN(6)
    acc[1][1] = MFMA8(a11, rf[1][1], acc[1][1]); FIN(7)
    if (dofin) { rsum[0] += ps[0]; rsum[1] += ps[1]; }
}

// Final epilogue for the last tile (no MFMA to hide under).
__device__ __forceinline__ void fin_all(const f32x16 (&pacc)[2][2], float (&rsum)[2]) {
    #pragma unroll
    for (int cc = 0; cc < 2; ++cc)
        #pragma unroll
        for (int rs = 0; rs < 2; ++rs) {
            float p = 0.f;
            #pragma unroll
            for (int g = 0; g < 16; ++g)
                p += __builtin_amdgcn_exp2f(pacc[cc][rs][g]);
            rsum[rs] += p;
        }
}

// ---------------------------------------------------------------------------
// K3: main fused MX-fp8 GEMM + exp row-sum, software-pipelined epilogue.
//   Grid 130*26 = 3380 blocks, 256 threads, 2x2 wave grid, 64x64 per wave.
//   acc double-buffered: exp(t-1) interleaves with MFMA(t). First MFMA of
//   each chain takes C=zero16 (no acc init). part holds RAW exp2 sums; the
//   -1/T shift cancels exactly in k_rowfin's log.
// ---------------------------------------------------------------------------
__global__ __launch_bounds__(256, 2) void k_main(const unsigned char* __restrict__ fb8,
                                                 const unsigned char* __restrict__ fb8s,
                                                 float* __restrict__ part) {
    __shared__ __align__(16) unsigned char lds[2][BN * 128];   // 2 x 16KB
    const int bid = blockIdx.x;
    const int rb = bid / CS, cs = bid % CS;
    const int tid = threadIdx.x;
    const int lane = tid & 63;
    const int wid  = tid >> 6;                 // 0..3
    const int wr = wid >> 1, wc = wid & 1;     // 2x2 wave grid
    const int l31 = lane & 31, lhi = lane >> 5;
    const int rw = rb * 128 + wr * 64;         // this wave's 64 rows

    int soff[4];
    #pragma unroll
    for (int i = 0; i < 4; ++i) {
        int flat = i * 256 + tid;
        int line = flat >> 4, p = flat & 15;
        int pl = p ^ (line & 15);
        soff[i] = (2 * line + (pl >> 3)) * 128 + (pl & 7) * 16;
    }

#define STAGE(T, B) { \
    const unsigned char* base_ = fb8 + ((size_t)(cs + (T) * CS)) * (BN * 128); \
    _Pragma("unroll") \
    for (int i_ = 0; i_ < 4; ++i_) \
        __builtin_amdgcn_global_load_lds( \
            (const __attribute__((address_space(1))) unsigned int*)(base_ + soff[i_]), \
            (__attribute__((address_space(3))) unsigned int*)(&lds[B][(i_ * 256 + tid) * 16]), \
            16, 0, 0); }

#define SYNC() { asm volatile("s_waitcnt vmcnt(0)" ::: "memory"); __builtin_amdgcn_s_barrier(); }

    // rf: B operand (scaled side), 2 row-groups x 2 K-steps x 32B
    i32x8 rf[2][2];
    #pragma unroll
    for (int rs = 0; rs < 2; ++rs)
        #pragma unroll
        for (int s = 0; s < 2; ++s)
            rf[rs][s] = *(const i32x8*)(fb8s + (size_t)(rw + rs * 32 + l31) * D + s * 64 + lhi * 32);

    f32x16 z16;
    #pragma unroll
    for (int e = 0; e < 16; ++e) z16[e] = 0.f;

    float rsum[2] = {0.f, 0.f};
    f32x16 accA[2][2], accB[2][2];

    STAGE(0, 0) SYNC()
    STAGE(1, 1)
    phase(lds[0], accA, accB, rf, z16, wc, l31, lhi, false, rsum);   // t=0
    SYNC()
    STAGE(2, 0)
    phase(lds[1], accB, accA, rf, z16, wc, l31, lhi, true, rsum);    // t=1, fin t=0
    SYNC()
    STAGE(3, 1)
    phase(lds[0], accA, accB, rf, z16, wc, l31, lhi, true, rsum);    // t=2, fin t=1
    SYNC()
    STAGE(4, 0)
    phase(lds[1], accB, accA, rf, z16, wc, l31, lhi, true, rsum);    // t=3, fin t=2
    SYNC()
    phase(lds[0], accA, accB, rf, z16, wc, l31, lhi, true, rsum);    // t=4, fin t=3
    fin_all(accA, rsum);                                             // fin t=4

    // combine c-halves (lane, lane^32 share a row), then the two wc waves.
    rsum[0] += __shfl_xor(rsum[0], 32);
    rsum[1] += __shfl_xor(rsum[1], 32);
    __shared__ float xred[2][2][32];   // [wr][rs][row]
    if (wc == 0 && lane < 32) {
        xred[wr][0][lane] = rsum[0];
        xred[wr][1][lane] = rsum[1];
    }
    __syncthreads();
    if (wc == 1 && lane < 32) {
        part[(size_t)cs * N + rw + lane]      = xred[wr][0][lane] + rsum[0];
        part[(size_t)cs * N + rw + 32 + lane] = xred[wr][1][lane] + rsum[1];
    }
#undef STAGE
#undef SYNC
}

// ---------------------------------------------------------------------------
// K4: per-row finalize. Redundant lp->S reduction + counts per block, then
// se = sum(part) - exp2(dd)  (raw domain; the 1/T shift cancels:
// lse = log(se_raw * 2^-SC) + 1/T = log(se_raw) since SC*ln2 == 1/T).
// ---------------------------------------------------------------------------
__global__ __launch_bounds__(256) void k_rowfin(const float* __restrict__ part,
                                                const float* __restrict__ ff,
                                                const float* __restrict__ ba,
                                                const float* __restrict__ nb,
                                                const float* __restrict__ lp,
                                                const long long* __restrict__ tgt,
                                                float* __restrict__ bsum) {
    __shared__ float sS[256];
    __shared__ float red[256];
    __shared__ int scnt[2];
    {   // S reduction (redundant per block; fixed order -> deterministic)
        int lab = threadIdx.x >> 7, d = threadIdx.x & 127;
        float s[4] = {0.f, 0.f, 0.f, 0.f};
        for (int b = 0; b < 260; b += 4) {
            #pragma unroll
            for (int j = 0; j < 4; ++j)
                s[j] += lp[((size_t)(b + j) * 2 + lab) * 128 + d];
        }
        sS[threadIdx.x] = (s[0] + s[1]) + (s[2] + s[3]);
        if (threadIdx.x < 64) {
            int c = 0;
            #pragma unroll
            for (int i = 0; i < 4; ++i) c += (int)tgt[threadIdx.x + 64 * i];
            #pragma unroll
            for (int m = 1; m < 64; m <<= 1) c += __shfl_xor(c, m);
            if (threadIdx.x == 0) { scnt[0] = (NQ - c) + KQ; scnt[1] = c + KQ; }
        }
    }
    __syncthreads();
    int r = blockIdx.x * 256 + threadIdx.x;
    float se = 0.f;
    #pragma unroll
    for (int c = 0; c < CS; ++c) se += part[(size_t)c * N + r];
    int lab = (r < NQ) ? (int)tgt[r] : ((r < NQ + KQ) ? 1 : 0);
    const float* fsrc = (r < NQ) ? (ff + (size_t)r * D)
                      : (r < NQ + KQ) ? (ba + (size_t)(r - NQ) * D)
                      : (nb + (size_t)(r - NQ - KQ) * D);
    const float4* frow = (const float4*)fsrc;
    const float4* srow = (const float4*)(sS + lab * 128);
    float dS = 0.f, dd = 0.f;
    #pragma unroll
    for (int i = 0; i < 32; ++i) {
        float4 f = frow[i];
        float4 s = srow[i];
        dS += f.x * s.x + f.y * s.y + f.z * s.z + f.w * s.w;
        // exact replica of the MFMA's diagonal contribution (same cvt ops)
        int wa  = __builtin_amdgcn_cvt_pk_fp8_f32(f.x, f.y, 0, false);
        int wb  = __builtin_amdgcn_cvt_pk_fp8_f32(f.z, f.w, 0, false);
        int wsa = __builtin_amdgcn_cvt_pk_fp8_f32(f.x * SC, f.y * SC, 0, false);
        int wsb = __builtin_amdgcn_cvt_pk_fp8_f32(f.z * SC, f.w * SC, 0, false);
        dd += __builtin_amdgcn_cvt_f32_fp8(wa, 0) * __builtin_amdgcn_cvt_f32_fp8(wsa, 0)
            + __builtin_amdgcn_cvt_f32_fp8(wa, 1) * __builtin_amdgcn_cvt_f32_fp8(wsa, 1)
            + __builtin_amdgcn_cvt_f32_fp8(wb, 0) * __builtin_amdgcn_cvt_f32_fp8(wsb, 0)
            + __builtin_amdgcn_cvt_f32_fp8(wb, 1) * __builtin_amdgcn_cvt_f32_fp8(wsb, 1);
    }
    se -= __builtin_amdgcn_exp2f(dd);
    float lse = logf(se);
    float P = (float)(scnt[lab] - 1);
    float mlpp = (dS - 1.0f) / (TEMPERATURE * P) - lse;
    red[threadIdx.x] = mlpp;
    __syncthreads();
    for (int s2 = 128; s2 > 0; s2 >>= 1) {
        if (threadIdx.x < s2) red[threadIdx.x] += red[threadIdx.x + s2];
        __syncthreads();
    }
    if (threadIdx.x == 0) bsum[blockIdx.x] = red[0];
}

// ---------------------------------------------------------------------------
// K5: final scalar.
// ---------------------------------------------------------------------------
__global__ __launch_bounds__(64) void k_final(const float* __restrict__ bsum,
                                              float* __restrict__ out) {
    float s = bsum[threadIdx.x];                 // RBF=65 > 64, lanes 0..63 valid
    if (threadIdx.x == 0) s += bsum[64];
    #pragma unroll
    for (int m = 1; m < 64; m <<= 1) s += __shfl_xor(s, m);
    if (threadIdx.x == 0) out[0] = -s / (float)N;
}

extern "C" void kernel_launch(void* const* d_in, const int* in_sizes, int n_in,
                              void* d_out, int out_size, void* d_ws, size_t ws_size,
                              hipStream_t stream) {
    const float* q       = (const float*)d_in[0];
    const float* ba      = (const float*)d_in[1];
    const float* nb      = (const float*)d_in[2];
    const long long* tgt = (const long long*)d_in[3];
    char* ws = (char*)d_ws;
    float*         ff   = (float*)(ws + OFF_F32);
    unsigned char* fb8  = (unsigned char*)(ws + OFF_8);
    unsigned char* fb8s = (unsigned char*)(ws + OFF_8S);
    float*         part = (float*)(ws + OFF_PART);
    float*         lp   = (float*)(ws + OFF_LP);
    float*         bsum = (float*)(ws + OFF_BSUM);

    k_prep  <<<260,      256, 0, stream>>>(q, ba, nb, tgt, ff, fb8, fb8s, lp);
    k_main  <<<RBM * CS, 256, 0, stream>>>(fb8, fb8s, part);
    k_rowfin<<<RBF,      256, 0, stream>>>(part, ff, ba, nb, lp, tgt, bsum);
    k_final <<<1,         64, 0, stream>>>(bsum, (float*)d_out);
}

// Round 10
// 77.842 us; speedup vs baseline: 1.0237x; 1.0237x over previous
//
#include <hip/hip_runtime.h>
#include <hip/hip_bf16.h>
#include <stdint.h>

#define TEMPERATURE 0.07f
#define SC 20.6099312f   // log2(e)/T  (SC*ln2 == 1/T; cancellation used in k_rowfin)

constexpr int NQ = 256;
constexpr int KQ = 8192;
constexpr int D  = 128;
constexpr int N  = NQ + 2 * KQ;   // 16640
constexpr int CS = 26;            // column splits (130 tiles / 26 = exactly 5 per block)
constexpr int BN = 128;           // columns per tile (fp8 tile = 16KB)
constexpr int RBM = N / 128;      // 130 row blocks for k_main
constexpr int RBF = N / 256;      // 65 blocks for k_rowfin

typedef float f32x16 __attribute__((ext_vector_type(16)));
typedef int   i32x4  __attribute__((ext_vector_type(4)));
typedef int   i32x8  __attribute__((ext_vector_type(8)));

// ---- workspace layout (bytes) ----
constexpr size_t OFF_F32  = 0;                                    // float feat [NQ][D] (q rows only)
constexpr size_t OFF_8    = OFF_F32  + (size_t)NQ * D * 4;        // fp8 feat (A side) [N][128]
constexpr size_t OFF_8S   = OFF_8    + (size_t)N * D;             // fp8 feat * SC (B side) [N][128]
constexpr size_t OFF_PART = OFF_8S   + (size_t)N * D;             // partials [CS][N]
constexpr size_t OFF_LP   = OFF_PART + (size_t)CS * N * 4;        // label partials [260][2][128]
constexpr size_t OFF_BSUM = OFF_LP   + (size_t)260 * 2 * 128 * 4; // blocksum [65]

#define MFMA8(a, b, c) __builtin_amdgcn_mfma_scale_f32_32x32x64_f8f6f4( \
    (a), (b), (c), 0, 0, 0, 0x7f7f7f7f, 0, 0x7f7f7f7f)

// ---------------------------------------------------------------------------
// K1: normalize features; emit f32 (q rows only) + two natural-row-major fp8
// copies (unscaled A side, SC-prescaled B side); per-label per-dim partials.
// ---------------------------------------------------------------------------
__global__ __launch_bounds__(256) void k_prep(const float* __restrict__ q,
                                              const float* __restrict__ ba,
                                              const float* __restrict__ nb,
                                              const long long* __restrict__ tgt,
                                              float* __restrict__ ff,
                                              unsigned char* __restrict__ fb8,
                                              unsigned char* __restrict__ fb8s,
                                              float* __restrict__ lp) {
    __shared__ float red[4][2][128];
    int wid = threadIdx.x >> 6, lane = threadIdx.x & 63;
    int rbase = blockIdx.x * 64 + wid * 16;
    float s0x = 0.f, s0y = 0.f, s1x = 0.f, s1y = 0.f;
    for (int i = 0; i < 16; ++i) {
        int r = rbase + i;
        const float* src = (r < NQ) ? (q + (size_t)r * D)
                         : (r < NQ + KQ) ? (ba + (size_t)(r - NQ) * D)
                         : (nb + (size_t)(r - NQ - KQ) * D);
        float2 v = *(const float2*)(src + lane * 2);
        float a = v.x, b = v.y;
        int lab;
        if (r < NQ) {
            float ss = a * a + b * b;
            #pragma unroll
            for (int m = 1; m < 64; m <<= 1) ss += __shfl_xor(ss, m);
            float scale = 1.0f / fmaxf(sqrtf(ss), 1e-12f);
            a *= scale; b *= scale;
            lab = (int)tgt[r];
            *(float2*)(ff + (size_t)r * D + lane * 2) = make_float2(a, b);
        } else {
            lab = (r < NQ + KQ) ? 1 : 0;
        }
        int w8  = __builtin_amdgcn_cvt_pk_fp8_f32(a, b, 0, false);
        int w8s = __builtin_amdgcn_cvt_pk_fp8_f32(a * SC, b * SC, 0, false);
        *(unsigned short*)(fb8  + (size_t)r * D + lane * 2) = (unsigned short)w8;
        *(unsigned short*)(fb8s + (size_t)r * D + lane * 2) = (unsigned short)w8s;
        if (lab) { s1x += a; s1y += b; } else { s0x += a; s0y += b; }
    }
    red[wid][0][lane * 2]     = s0x;
    red[wid][0][lane * 2 + 1] = s0y;
    red[wid][1][lane * 2]     = s1x;
    red[wid][1][lane * 2 + 1] = s1y;
    __syncthreads();
    int lab2 = threadIdx.x >> 7, d = threadIdx.x & 127;
    float s = red[0][lab2][d] + red[1][lab2][d] + red[2][lab2][d] + red[3][lab2][d];
    lp[((size_t)blockIdx.x * 2 + lab2) * 128 + d] = s;
}

// FIN(c): exp-epilogue slice of the PREVIOUS tile (pacc), 8 exps, pairwise
// accumulated (float2 -> v_pk_add_f32 eligible).
#define FIN(c) if (dofin) { const f32x16& A_ = pacc[((c) >> 2) & 1][((c) >> 1) & 1]; \
    float2 t_; \
    t_.x = __builtin_amdgcn_exp2f(A_[(((c) & 1) << 3) + 0]) + __builtin_amdgcn_exp2f(A_[(((c) & 1) << 3) + 2]); \
    t_.y = __builtin_amdgcn_exp2f(A_[(((c) & 1) << 3) + 1]) + __builtin_amdgcn_exp2f(A_[(((c) & 1) << 3) + 3]); \
    t_.x += __builtin_amdgcn_exp2f(A_[(((c) & 1) << 3) + 4]) + __builtin_amdgcn_exp2f(A_[(((c) & 1) << 3) + 6]); \
    t_.y += __builtin_amdgcn_exp2f(A_[(((c) & 1) << 3) + 5]) + __builtin_amdgcn_exp2f(A_[(((c) & 1) << 3) + 7]); \
    ps2[((c) >> 1) & 1].x += t_.x; ps2[((c) >> 1) & 1].y += t_.y; }

// One super-phase: 8 MFMAs of this tile + interleaved exp-epilogue of the
// previous tile. Schedule pinned via sched_group_barrier: per group
// {1 MFMA, 16 VALU} so trans work issues in every MFMA's pipe shadow.
__device__ __forceinline__ void phase(const unsigned char* buf, const int (&lofs)[4][2],
                                      f32x16 (&acc)[2][2], const f32x16 (&pacc)[2][2],
                                      const i32x8 (&rf)[2][2], const f32x16& z16,
                                      bool dofin, float (&rsum)[2]) {
    i32x4 lo, hi;
    lo = *(const i32x4*)(buf + lofs[0][0]); hi = *(const i32x4*)(buf + lofs[0][1]);
    i32x8 a00 = {lo[0], lo[1], lo[2], lo[3], hi[0], hi[1], hi[2], hi[3]};
    lo = *(const i32x4*)(buf + lofs[1][0]); hi = *(const i32x4*)(buf + lofs[1][1]);
    i32x8 a10 = {lo[0], lo[1], lo[2], lo[3], hi[0], hi[1], hi[2], hi[3]};
    lo = *(const i32x4*)(buf + lofs[2][0]); hi = *(const i32x4*)(buf + lofs[2][1]);
    i32x8 a01 = {lo[0], lo[1], lo[2], lo[3], hi[0], hi[1], hi[2], hi[3]};
    lo = *(const i32x4*)(buf + lofs[3][0]); hi = *(const i32x4*)(buf + lofs[3][1]);
    i32x8 a11 = {lo[0], lo[1], lo[2], lo[3], hi[0], hi[1], hi[2], hi[3]};

    float2 ps2[2] = {{0.f, 0.f}, {0.f, 0.f}};
    acc[0][0] = MFMA8(a00, rf[0][0], z16);       FIN(0)
    acc[0][0] = MFMA8(a10, rf[0][1], acc[0][0]); FIN(1)
    acc[0][1] = MFMA8(a00, rf[1][0], z16);       FIN(2)
    acc[0][1] = MFMA8(a10, rf[1][1], acc[0][1]); FIN(3)
    acc[1][0] = MFMA8(a01, rf[0][0], z16);       FIN(4)
    acc[1][0] = MFMA8(a11, rf[0][1], acc[1][0]); FIN(5)
    acc[1][1] = MFMA8(a01, rf[1][0], z16);       FIN(6)
    acc[1][1] = MFMA8(a11, rf[1][1], acc[1][1]); FIN(7)
    if (dofin) {
        rsum[0] += ps2[0].x + ps2[0].y;
        rsum[1] += ps2[1].x + ps2[1].y;
    }
    // compile-time schedule pin (T19): ds_reads first, then 1:16 MFMA:VALU.
    __builtin_amdgcn_sched_group_barrier(0x100, 8, 0);   // 8 x ds_read_b128
    #pragma unroll
    for (int g = 0; g < 8; ++g) {
        __builtin_amdgcn_sched_group_barrier(0x008, 1, 0);   // 1 MFMA
        __builtin_amdgcn_sched_group_barrier(0x002, 16, 0);  // 16 VALU/trans
    }
}

// Final epilogue for the last tile (no MFMA to hide under).
__device__ __forceinline__ void fin_all(const f32x16 (&pacc)[2][2], float (&rsum)[2]) {
    #pragma unroll
    for (int cc = 0; cc < 2; ++cc)
        #pragma unroll
        for (int rs = 0; rs < 2; ++rs) {
            float2 p = {0.f, 0.f};
            #pragma unroll
            for (int g = 0; g < 8; ++g) {
                p.x += __builtin_amdgcn_exp2f(pacc[cc][rs][2 * g]);
                p.y += __builtin_amdgcn_exp2f(pacc[cc][rs][2 * g + 1]);
            }
            rsum[rs] += p.x + p.y;
        }
}

// ---------------------------------------------------------------------------
// K3: main fused MX-fp8 GEMM + exp row-sum, SGB-pinned pipelined epilogue.
//   Grid 130*26 = 3380 blocks, 256 threads, 2x2 wave grid, 64x64 per wave.
//   acc double-buffered: exp(t-1) interleaves with MFMA(t). part holds RAW
//   exp2 sums; the -1/T shift cancels in k_rowfin's log.
// ---------------------------------------------------------------------------
__global__ __launch_bounds__(256, 2) void k_main(const unsigned char* __restrict__ fb8,
                                                 const unsigned char* __restrict__ fb8s,
                                                 float* __restrict__ part) {
    __shared__ __align__(16) unsigned char lds[2][BN * 128];   // 2 x 16KB
    const int bid = blockIdx.x;
    const int rb = bid / CS, cs = bid % CS;
    const int tid = threadIdx.x;
    const int lane = tid & 63;
    const int wid  = tid >> 6;                 // 0..3
    const int wr = wid >> 1, wc = wid & 1;     // 2x2 wave grid
    const int l31 = lane & 31, lhi = lane >> 5;
    const int rw = rb * 128 + wr * 64;         // this wave's 64 rows

    int soff[4];
    #pragma unroll
    for (int i = 0; i < 4; ++i) {
        int flat = i * 256 + tid;
        int line = flat >> 4, p = flat & 15;
        int pl = p ^ (line & 15);
        soff[i] = (2 * line + (pl >> 3)) * 128 + (pl & 7) * 16;
    }

    // hoisted LDS read offsets: [cc*2+s][lo/hi] (R7-verified 0-conflict layout)
    int lofs[4][2];
    #pragma unroll
    for (int cc = 0; cc < 2; ++cc)
        #pragma unroll
        for (int s = 0; s < 2; ++s) {
            int crow = wc * 64 + cc * 32 + l31;
            int line = crow >> 1;
            int pb = ((crow & 1) << 3) + s * 4 + lhi * 2;
            lofs[cc * 2 + s][0] = line * 256 + ((pb       ^ (line & 15)) << 4);
            lofs[cc * 2 + s][1] = line * 256 + (((pb + 1) ^ (line & 15)) << 4);
        }

#define STAGE(T, B) { \
    const unsigned char* base_ = fb8 + ((size_t)(cs + (T) * CS)) * (BN * 128); \
    _Pragma("unroll") \
    for (int i_ = 0; i_ < 4; ++i_) \
        __builtin_amdgcn_global_load_lds( \
            (const __attribute__((address_space(1))) unsigned int*)(base_ + soff[i_]), \
            (__attribute__((address_space(3))) unsigned int*)(&lds[B][(i_ * 256 + tid) * 16]), \
            16, 0, 0); }

#define SYNC() { asm volatile("s_waitcnt vmcnt(0)" ::: "memory"); __builtin_amdgcn_s_barrier(); }

    // rf: B operand (scaled side), 2 row-groups x 2 K-steps x 32B
    i32x8 rf[2][2];
    #pragma unroll
    for (int rs = 0; rs < 2; ++rs)
        #pragma unroll
        for (int s = 0; s < 2; ++s)
            rf[rs][s] = *(const i32x8*)(fb8s + (size_t)(rw + rs * 32 + l31) * D + s * 64 + lhi * 32);

    f32x16 z16;
    #pragma unroll
    for (int e = 0; e < 16; ++e) z16[e] = 0.f;

    float rsum[2] = {0.f, 0.f};
    f32x16 accA[2][2], accB[2][2];

    const unsigned char* b0 = &lds[0][0];
    const unsigned char* b1 = &lds[1][0];

    STAGE(0, 0) SYNC()
    STAGE(1, 1)
    phase(b0, lofs, accA, accB, rf, z16, false, rsum);   // t=0
    SYNC()
    STAGE(2, 0)
    phase(b1, lofs, accB, accA, rf, z16, true, rsum);    // t=1, fin t=0
    SYNC()
    STAGE(3, 1)
    phase(b0, lofs, accA, accB, rf, z16, true, rsum);    // t=2, fin t=1
    SYNC()
    STAGE(4, 0)
    phase(b1, lofs, accB, accA, rf, z16, true, rsum);    // t=3, fin t=2
    SYNC()
    phase(b0, lofs, accA, accB, rf, z16, true, rsum);    // t=4, fin t=3
    fin_all(accA, rsum);                                 // fin t=4

    // combine c-halves (lane, lane^32 share a row), then the two wc waves.
    rsum[0] += __shfl_xor(rsum[0], 32);
    rsum[1] += __shfl_xor(rsum[1], 32);
    __shared__ float xred[2][2][32];   // [wr][rs][row]
    if (wc == 0 && lane < 32) {
        xred[wr][0][lane] = rsum[0];
        xred[wr][1][lane] = rsum[1];
    }
    __syncthreads();
    if (wc == 1 && lane < 32) {
        part[(size_t)cs * N + rw + lane]      = xred[wr][0][lane] + rsum[0];
        part[(size_t)cs * N + rw + 32 + lane] = xred[wr][1][lane] + rsum[1];
    }
#undef STAGE
#undef SYNC
}

// ---------------------------------------------------------------------------
// K4: per-row finalize. Redundant lp->S reduction + counts per block, then
// se = sum(part) - exp2(dd); lse = log(se_raw) (the 1/T shift cancels).
// ---------------------------------------------------------------------------
__global__ __launch_bounds__(256) void k_rowfin(const float* __restrict__ part,
                                                const float* __restrict__ ff,
                                                const float* __restrict__ ba,
                                                const float* __restrict__ nb,
                                                const float* __restrict__ lp,
                                                const long long* __restrict__ tgt,
                                                float* __restrict__ bsum) {
    __shared__ float sS[256];
    __shared__ float red[256];
    __shared__ int scnt[2];
    {   // S reduction (redundant per block; fixed order -> deterministic)
        int lab = threadIdx.x >> 7, d = threadIdx.x & 127;
        float s[4] = {0.f, 0.f, 0.f, 0.f};
        for (int b = 0; b < 260; b += 4) {
            #pragma unroll
            for (int j = 0; j < 4; ++j)
                s[j] += lp[((size_t)(b + j) * 2 + lab) * 128 + d];
        }
        sS[threadIdx.x] = (s[0] + s[1]) + (s[2] + s[3]);
        if (threadIdx.x < 64) {
            int c = 0;
            #pragma unroll
            for (int i = 0; i < 4; ++i) c += (int)tgt[threadIdx.x + 64 * i];
            #pragma unroll
            for (int m = 1; m < 64; m <<= 1) c += __shfl_xor(c, m);
            if (threadIdx.x == 0) { scnt[0] = (NQ - c) + KQ; scnt[1] = c + KQ; }
        }
    }
    __syncthreads();
    int r = blockIdx.x * 256 + threadIdx.x;
    float se = 0.f;
    #pragma unroll
    for (int c = 0; c < CS; ++c) se += part[(size_t)c * N + r];
    int lab = (r < NQ) ? (int)tgt[r] : ((r < NQ + KQ) ? 1 : 0);
    const float* fsrc = (r < NQ) ? (ff + (size_t)r * D)
                      : (r < NQ + KQ) ? (ba + (size_t)(r - NQ) * D)
                      : (nb + (size_t)(r - NQ - KQ) * D);
    const float4* frow = (const float4*)fsrc;
    const float4* srow = (const float4*)(sS + lab * 128);
    float dS = 0.f, dd = 0.f;
    #pragma unroll
    for (int i = 0; i < 32; ++i) {
        float4 f = frow[i];
        float4 s = srow[i];
        dS += f.x * s.x + f.y * s.y + f.z * s.z + f.w * s.w;
        // exact replica of the MFMA's diagonal contribution (same cvt ops)
        int wa  = __builtin_amdgcn_cvt_pk_fp8_f32(f.x, f.y, 0, false);
        int wb  = __builtin_amdgcn_cvt_pk_fp8_f32(f.z, f.w, 0, false);
        int wsa = __builtin_amdgcn_cvt_pk_fp8_f32(f.x * SC, f.y * SC, 0, false);
        int wsb = __builtin_amdgcn_cvt_pk_fp8_f32(f.z * SC, f.w * SC, 0, false);
        dd += __builtin_amdgcn_cvt_f32_fp8(wa, 0) * __builtin_amdgcn_cvt_f32_fp8(wsa, 0)
            + __builtin_amdgcn_cvt_f32_fp8(wa, 1) * __builtin_amdgcn_cvt_f32_fp8(wsa, 1)
            + __builtin_amdgcn_cvt_f32_fp8(wb, 0) * __builtin_amdgcn_cvt_f32_fp8(wsb, 0)
            + __builtin_amdgcn_cvt_f32_fp8(wb, 1) * __builtin_amdgcn_cvt_f32_fp8(wsb, 1);
    }
    se -= __builtin_amdgcn_exp2f(dd);
    float lse = logf(se);
    float P = (float)(scnt[lab] - 1);
    float mlpp = (dS - 1.0f) / (TEMPERATURE * P) - lse;
    red[threadIdx.x] = mlpp;
    __syncthreads();
    for (int s2 = 128; s2 > 0; s2 >>= 1) {
        if (threadIdx.x < s2) red[threadIdx.x] += red[threadIdx.x + s2];
        __syncthreads();
    }
    if (threadIdx.x == 0) bsum[blockIdx.x] = red[0];
}

// ---------------------------------------------------------------------------
// K5: final scalar.
// ---------------------------------------------------------------------------
__global__ __launch_bounds__(64) void k_final(const float* __restrict__ bsum,
                                              float* __restrict__ out) {
    float s = bsum[threadIdx.x];                 // RBF=65 > 64, lanes 0..63 valid
    if (threadIdx.x == 0) s += bsum[64];
    #pragma unroll
    for (int m = 1; m < 64; m <<= 1) s += __shfl_xor(s, m);
    if (threadIdx.x == 0) out[0] = -s / (float)N;
}

extern "C" void kernel_launch(void* const* d_in, const int* in_sizes, int n_in,
                              void* d_out, int out_size, void* d_ws, size_t ws_size,
                              hipStream_t stream) {
    const float* q       = (const float*)d_in[0];
    const float* ba      = (const float*)d_in[1];
    const float* nb      = (const float*)d_in[2];
    const long long* tgt = (const long long*)d_in[3];
    char* ws = (char*)d_ws;
    float*         ff   = (float*)(ws + OFF_F32);
    unsigned char* fb8  = (unsigned char*)(ws + OFF_8);
    unsigned char* fb8s = (unsigned char*)(ws + OFF_8S);
    float*         part = (float*)(ws + OFF_PART);
    float*         lp   = (float*)(ws + OFF_LP);
    float*         bsum = (float*)(ws + OFF_BSUM);

    k_prep  <<<260,      256, 0, stream>>>(q, ba, nb, tgt, ff, fb8, fb8s, lp);
    k_main  <<<RBM * CS, 256, 0, stream>>>(fb8, fb8s, part);
    k_rowfin<<<RBF,      256, 0, stream>>>(part, ff, ba, nb, lp, tgt, bsum);
    k_final <<<1,         64, 0, stream>>>(bsum, (float*)d_out);
}